// Round 2
// baseline (442.459 us; speedup 1.0000x reference)
//
#include <hip/hip_runtime.h>

// NoRA: out = P(x) / (1 + |Z(x)*x|), per-group coefficients adapted by LoRA.
// B=4, L=4096, D=4096, G=8, Dg=512, R=3. All tensors fp32 (round-1 NaN proved
// the bf16 reinterpretation wrong). Memory-bound: 256 MB in + 256 MB out
// => roofline ~81 us @ 6.3 TB/s achievable.

#define NG 6   // numerator coeffs per group
#define DG 4   // denominator coeffs per group
#define GROUPS 8
#define RANK 3
#define SCALING 2.0f
#define EPS 1e-6f

__global__ __launch_bounds__(256) void nora_kernel(
    const float* __restrict__ x,          // [B*L*D]
    const float* __restrict__ base_num,   // [G,6]
    const float* __restrict__ base_den,   // [G,4]
    const float* __restrict__ lA_num,     // [R,6]
    const float* __restrict__ lB_num,     // [G,R]
    const float* __restrict__ lA_den,     // [R,4]
    const float* __restrict__ lB_den,     // [G,R]
    float* __restrict__ out,
    int n_vec)                            // total / 4
{
    __shared__ float s_num[GROUPS][NG];
    __shared__ float s_den[GROUPS][DG];

    const int tid = threadIdx.x;
    if (tid < GROUPS * NG) {                       // 48 threads: numerator coeffs
        const int g = tid / NG, k = tid % NG;
        float s = 0.f;
        #pragma unroll
        for (int r = 0; r < RANK; ++r)
            s += lB_num[g * RANK + r] * lA_num[r * NG + k];
        s_num[g][k] = base_num[tid] + SCALING * s;
    } else if (tid < GROUPS * NG + GROUPS * DG) {  // 32 threads: denominator coeffs
        const int t = tid - GROUPS * NG;
        const int g = t / DG, k = t % DG;
        float s = 0.f;
        #pragma unroll
        for (int r = 0; r < RANK; ++r)
            s += lB_den[g * RANK + r] * lA_den[r * DG + k];
        s_den[g][k] = base_den[t] + SCALING * s + EPS;
    }
    __syncthreads();

    const int stride = gridDim.x * blockDim.x;
    for (int v = blockIdx.x * blockDim.x + tid; v < n_vec; v += stride) {
        // element index = 4*v; channel = (4*v) % 4096; group = channel / 512
        // 4 | 512 so all 4 elements of the vector share one group.
        const int g = (v >> 7) & (GROUPS - 1);

        const float a0 = s_num[g][0], a1 = s_num[g][1], a2 = s_num[g][2];
        const float a3 = s_num[g][3], a4 = s_num[g][4], a5 = s_num[g][5];
        const float b0 = s_den[g][0], b1 = s_den[g][1];
        const float b2 = s_den[g][2], b3 = s_den[g][3];

        const float4 in = ((const float4*)x)[v];
        float xs[4] = {in.x, in.y, in.z, in.w};
        float rs[4];

        #pragma unroll
        for (int j = 0; j < 4; ++j) {
            const float xv = xs[j];
            // P(x) = a0 + a1 x + ... + a5 x^5 (Horner)
            float p = fmaf(a5, xv, a4);
            p = fmaf(p, xv, a3);
            p = fmaf(p, xv, a2);
            p = fmaf(p, xv, a1);
            p = fmaf(p, xv, a0);
            // Z(x) = b0 + b1 x + b2 x^2 + b3 x^3 (Horner); Q = 1 + |Z*x|
            float z = fmaf(b3, xv, b2);
            z = fmaf(z, xv, b1);
            z = fmaf(z, xv, b0);
            const float q = 1.0f + fabsf(z * xv);
            rs[j] = p * __builtin_amdgcn_rcpf(q);
        }

        float4 o;
        o.x = rs[0]; o.y = rs[1]; o.z = rs[2]; o.w = rs[3];
        ((float4*)out)[v] = o;
    }
}

extern "C" void kernel_launch(void* const* d_in, const int* in_sizes, int n_in,
                              void* d_out, int out_size, void* d_ws, size_t ws_size,
                              hipStream_t stream) {
    const float* x   = (const float*)d_in[0];
    const float* bn  = (const float*)d_in[1];
    const float* bd  = (const float*)d_in[2];
    const float* lAn = (const float*)d_in[3];
    const float* lBn = (const float*)d_in[4];
    const float* lAd = (const float*)d_in[5];
    const float* lBd = (const float*)d_in[6];
    float* out = (float*)d_out;

    const int n = in_sizes[0];          // 4*4096*4096 = 67108864, divisible by 4
    const int n_vec = n / 4;            // 16777216 float4 vectors

    const int block = 256;
    const int grid  = 8192;             // grid-stride: 8 float4 per thread
    hipLaunchKernelGGL(nora_kernel, dim3(grid), dim3(block), 0, stream,
                       x, bn, bd, lAn, lBn, lAd, lBd, out, n_vec);
}